// Round 3
// baseline (454.035 us; speedup 1.0000x reference)
//
#include <hip/hip_runtime.h>
#include <hip/hip_bf16.h>

#define H    128
#define HIN  384
#define FIN  512      // H + HIN
#define KNB  48
#define DFF  512
#define NNODES 8192
#define NNB_F (KNB*HIN)   // floats of h_E per node

typedef float f32x4 __attribute__((ext_vector_type(4)));
typedef short bf16x8 __attribute__((ext_vector_type(8)));

__device__ __forceinline__ short bfs(float x){
  __hip_bfloat16 h = __float2bfloat16(x);   // RNE; compiler can fuse pairs into v_cvt_pk_bf16_f32
  return *(short*)&h;
}

__device__ __forceinline__ bf16x8 pack8(float4 a, float4 b){
  bf16x8 o;
  o[0]=bfs(a.x); o[1]=bfs(a.y); o[2]=bfs(a.z); o[3]=bfs(a.w);
  o[4]=bfs(b.x); o[5]=bfs(b.y); o[6]=bfs(b.z); o[7]=bfs(b.w);
  return o;
}

__device__ __forceinline__ float gelu_f(float x){
  return 0.5f * x * (1.0f + erff(x * 0.70710678118654752f));
}

__device__ __forceinline__ f32x4 zero4(){ f32x4 z; z[0]=0.f;z[1]=0.f;z[2]=0.f;z[3]=0.f; return z; }

// ---------------- kernel 0: convert weights fp32 -> bf16 into ws ----------------
__global__ __launch_bounds__(256) void k_convert(
    const float* __restrict__ W1, const float* __restrict__ W2,
    const float* __restrict__ W3, const float* __restrict__ Win,
    const float* __restrict__ Wout, unsigned short* __restrict__ dst)
{
  int i0 = (blockIdx.x*256 + threadIdx.x)*4;
  #pragma unroll
  for (int t=0;t<4;t++){
    int idx = i0 + t;
    float v;
    if      (idx <  65536) v = W1[idx];
    else if (idx <  81920) v = W2[idx-65536];
    else if (idx <  98304) v = W3[idx-81920];
    else if (idx < 163840) v = Win[idx-98304];
    else                   v = Wout[idx-163840];
    dst[idx] = (unsigned short)bfs(v);
  }
}

// ---------------- kernel 1: bias1[node][o] = h_V @ W1[:, :128]^T + W1_b ----------------
__global__ __launch_bounds__(256) void k_bias1(
    const float* __restrict__ hV, const unsigned short* __restrict__ wW1,
    const float* __restrict__ W1b, float* __restrict__ bias1)
{
  int tid = threadIdx.x;
  int wid = tid>>6, lane = tid&63;
  int lr = lane&15, lg = lane>>4;
  int m0 = (blockIdx.x*4 + wid)*16;

  f32x4 acc[8];
  #pragma unroll
  for (int i=0;i<8;i++) acc[i] = zero4();

  #pragma unroll
  for (int ks=0; ks<4; ks++){
    const float* p = hV + (size_t)(m0+lr)*H + ks*32 + lg*8;
    bf16x8 a = pack8(*(const float4*)p, *(const float4*)(p+4));
    #pragma unroll
    for (int nt=0; nt<8; nt++){
      bf16x8 b = *(const bf16x8*)(wW1 + (size_t)(nt*16+lr)*FIN + ks*32 + lg*8);
      acc[nt] = __builtin_amdgcn_mfma_f32_16x16x32_bf16(a, b, acc[nt], 0,0,0);
    }
  }
  #pragma unroll
  for (int nt=0; nt<8; nt++){
    int col = nt*16 + lr;
    float bv = W1b[col];
    #pragma unroll
    for (int e=0;e<4;e++){
      int row = lg*4 + e;
      bias1[(size_t)(m0+row)*H + col] = acc[nt][e] + bv;
    }
  }
}

// ---------------- kernel 2: per-node message chain + LN1 ----------------
// grid = 8192 blocks (one node each), 256 threads (4 waves)
// A-operand (h_E) is read global->VGPR directly: all 4 waves share the same
// 6KB/k-step working set (L1-hit for 3 of 4 waves); no LDS staging phase.
__global__ __launch_bounds__(256,4) void k_message(
    const float* __restrict__ hV, const float* __restrict__ hE,
    const float* __restrict__ maskA,
    const unsigned short* __restrict__ wW1, const unsigned short* __restrict__ wW2,
    const unsigned short* __restrict__ wW3,
    const float* __restrict__ W2b, const float* __restrict__ W3b,
    const float* __restrict__ ln1w, const float* __restrict__ ln1b,
    const float* __restrict__ bias1, float* __restrict__ hmid)
{
  __shared__ __align__(16) unsigned short sG[48*136];  // G1 then G2 (reused)
  __shared__ float sMask[48];
  __shared__ float sBias[128];
  __shared__ float sDh[128];

  int node = blockIdx.x;
  int tid  = threadIdx.x;
  if (tid < 48)  sMask[tid] = maskA[(size_t)node*KNB + tid];
  if (tid < 128) sBias[tid] = bias1[(size_t)node*H + tid];

  int wid = tid>>6, lane = tid&63;
  int lr = lane&15, lg = lane>>4;
  const float* hEn = hE + (size_t)node * NNB_F;
  const float* aBase = hEn + (size_t)lr*HIN + lg*8;

  // ---- GEMM1: [48 x 384](global fp32) @ W1e^T -> [48 x 128] ----
  f32x4 acc1[3][2];
  #pragma unroll
  for (int mt=0;mt<3;mt++){ acc1[mt][0]=zero4(); acc1[mt][1]=zero4(); }

  #pragma unroll 2
  for (int ks=0; ks<12; ks++){
    bf16x8 a[3];
    #pragma unroll
    for (int mt=0;mt<3;mt++){
      const float* p = aBase + (size_t)mt*16*HIN + ks*32;
      a[mt] = pack8(*(const float4*)p, *(const float4*)(p+4));
    }
    #pragma unroll
    for (int j=0;j<2;j++){
      int nt = wid*2 + j;
      bf16x8 b = *(const bf16x8*)(wW1 + (size_t)(nt*16+lr)*FIN + (H + ks*32 + lg*8));
      #pragma unroll
      for (int mt=0;mt<3;mt++)
        acc1[mt][j] = __builtin_amdgcn_mfma_f32_16x16x32_bf16(a[mt], b, acc1[mt][j], 0,0,0);
    }
  }
  __syncthreads();   // sBias/sMask visible; all GEMM1 done before sG writes

  // epilogue 1: + bias1, gelu, write G1
  #pragma unroll
  for (int j=0;j<2;j++){
    int col = (wid*2+j)*16 + lr;
    float bv = sBias[col];
    #pragma unroll
    for (int mt=0;mt<3;mt++){
      #pragma unroll
      for (int e=0;e<4;e++){
        float g = gelu_f(acc1[mt][j][e] + bv);
        int row = mt*16 + lg*4 + e;
        sG[row*136 + col] = (unsigned short)bfs(g);
      }
    }
  }
  __syncthreads();

  // ---- GEMM2: [48 x 128] @ W2^T ----
  f32x4 acc2[3][2];
  #pragma unroll
  for (int mt=0;mt<3;mt++){ acc2[mt][0]=zero4(); acc2[mt][1]=zero4(); }
  #pragma unroll
  for (int ks=0; ks<4; ks++){
    bf16x8 a[3];
    #pragma unroll
    for (int mt=0;mt<3;mt++)
      a[mt] = *(const bf16x8*)(sG + (mt*16+lr)*136 + ks*32 + lg*8);
    #pragma unroll
    for (int j=0;j<2;j++){
      int nt = wid*2 + j;
      bf16x8 b = *(const bf16x8*)(wW2 + (size_t)(nt*16+lr)*H + ks*32 + lg*8);
      #pragma unroll
      for (int mt=0;mt<3;mt++)
        acc2[mt][j] = __builtin_amdgcn_mfma_f32_16x16x32_bf16(a[mt], b, acc2[mt][j], 0,0,0);
    }
  }
  __syncthreads();   // all reads of G1 done before overwrite

  // epilogue 2: + b2, gelu, write G2 (same buffer)
  #pragma unroll
  for (int j=0;j<2;j++){
    int col = (wid*2+j)*16 + lr;
    float bv = W2b[col];
    #pragma unroll
    for (int mt=0;mt<3;mt++){
      #pragma unroll
      for (int e=0;e<4;e++){
        float g = gelu_f(acc2[mt][j][e] + bv);
        int row = mt*16 + lg*4 + e;
        sG[row*136 + col] = (unsigned short)bfs(g);
      }
    }
  }
  __syncthreads();

  // ---- GEMM3: [48 x 128] @ W3^T ----
  f32x4 acc3[3][2];
  #pragma unroll
  for (int mt=0;mt<3;mt++){ acc3[mt][0]=zero4(); acc3[mt][1]=zero4(); }
  #pragma unroll
  for (int ks=0; ks<4; ks++){
    bf16x8 a[3];
    #pragma unroll
    for (int mt=0;mt<3;mt++)
      a[mt] = *(const bf16x8*)(sG + (mt*16+lr)*136 + ks*32 + lg*8);
    #pragma unroll
    for (int j=0;j<2;j++){
      int nt = wid*2 + j;
      bf16x8 b = *(const bf16x8*)(wW3 + (size_t)(nt*16+lr)*H + ks*32 + lg*8);
      #pragma unroll
      for (int mt=0;mt<3;mt++)
        acc3[mt][j] = __builtin_amdgcn_mfma_f32_16x16x32_bf16(a[mt], b, acc3[mt][j], 0,0,0);
    }
  }
  // epilogue 3: + b3, * mask_attend, column-sum over the 48 rows
  #pragma unroll
  for (int j=0;j<2;j++){
    int col = (wid*2+j)*16 + lr;
    float bv = W3b[col];
    float p = 0.f;
    #pragma unroll
    for (int mt=0;mt<3;mt++){
      #pragma unroll
      for (int e=0;e<4;e++){
        int row = mt*16 + lg*4 + e;
        p += (acc3[mt][j][e] + bv) * sMask[row];
      }
    }
    p += __shfl_xor(p, 16);
    p += __shfl_xor(p, 32);
    if (lane < 16) sDh[(wid*2+j)*16 + lane] = p;
  }
  __syncthreads();

  // ---- LN1 (wave 0): h = LN(h_V + dh/30) -> hmid ----
  if (wid == 0){
    int c0 = lane, c1 = lane + 64;
    float t0 = hV[(size_t)node*H + c0] + sDh[c0]*(1.0f/30.0f);
    float t1 = hV[(size_t)node*H + c1] + sDh[c1]*(1.0f/30.0f);
    float s = t0 + t1, q = t0*t0 + t1*t1;
    #pragma unroll
    for (int off=1; off<64; off<<=1){ s += __shfl_xor(s, off); q += __shfl_xor(q, off); }
    float mu  = s * (1.0f/128.0f);
    float var = q * (1.0f/128.0f) - mu*mu;
    float rs  = rsqrtf(var + 1e-5f);
    hmid[(size_t)node*H + c0] = (t0-mu)*rs*ln1w[c0] + ln1b[c0];
    hmid[(size_t)node*H + c1] = (t1-mu)*rs*ln1w[c1] + ln1b[c1];
  }
}

// ---------------- kernel 3: FFN + LN2 + mask_V -> out (in place over hmid) ----------------
// grid = 256 blocks (32 nodes each), 256 threads
__global__ __launch_bounds__(256) void k_ffn(
    const float* __restrict__ hmid, const unsigned short* __restrict__ wWin,
    const unsigned short* __restrict__ wWout,
    const float* __restrict__ Winb, const float* __restrict__ Woutb,
    const float* __restrict__ ln2w, const float* __restrict__ ln2b,
    const float* __restrict__ maskV, float* __restrict__ out)
{
  __shared__ __align__(16) unsigned short sH[32*136];
  __shared__ __align__(16) unsigned short sU[32*520];
  __shared__ float sT[32*132];

  int tid = threadIdx.x;
  int m0 = blockIdx.x * 32;

  #pragma unroll
  for (int i=0;i<2;i++){
    int c = i*256 + tid;         // 512 chunks of 8
    int row = c>>4, cir = c&15;
    const float* p = hmid + (size_t)(m0+row)*H + cir*8;
    *(bf16x8*)(sH + row*136 + cir*8) = pack8(*(const float4*)p, *(const float4*)(p+4));
  }
  __syncthreads();

  int wid = tid>>6, lane = tid&63;
  int lr = lane&15, lg = lane>>4;

  // ---- GEMM in: [32 x 128] @ Win^T -> [32 x 512], gelu ----
  f32x4 acc[2][8];
  #pragma unroll
  for (int mt=0;mt<2;mt++)
    #pragma unroll
    for (int j=0;j<8;j++) acc[mt][j] = zero4();

  #pragma unroll
  for (int ks=0; ks<4; ks++){
    bf16x8 a[2];
    #pragma unroll
    for (int mt=0;mt<2;mt++)
      a[mt] = *(const bf16x8*)(sH + (mt*16+lr)*136 + ks*32 + lg*8);
    #pragma unroll
    for (int j=0;j<8;j++){
      int nt = wid*8 + j;
      bf16x8 b = *(const bf16x8*)(wWin + (size_t)(nt*16+lr)*H + ks*32 + lg*8);
      #pragma unroll
      for (int mt=0;mt<2;mt++)
        acc[mt][j] = __builtin_amdgcn_mfma_f32_16x16x32_bf16(a[mt], b, acc[mt][j], 0,0,0);
    }
  }
  #pragma unroll
  for (int j=0;j<8;j++){
    int col = (wid*8+j)*16 + lr;
    float bv = Winb[col];
    #pragma unroll
    for (int mt=0;mt<2;mt++){
      #pragma unroll
      for (int e=0;e<4;e++){
        float g = gelu_f(acc[mt][j][e] + bv);
        int row = mt*16 + lg*4 + e;
        sU[row*520 + col] = (unsigned short)bfs(g);
      }
    }
  }
  __syncthreads();

  // ---- GEMM out: [32 x 512] @ Wout^T -> [32 x 128], +bias +residual ----
  f32x4 accO[2][2];
  #pragma unroll
  for (int mt=0;mt<2;mt++){ accO[mt][0]=zero4(); accO[mt][1]=zero4(); }

  for (int ks=0; ks<16; ks++){
    bf16x8 a[2];
    #pragma unroll
    for (int mt=0;mt<2;mt++)
      a[mt] = *(const bf16x8*)(sU + (mt*16+lr)*520 + ks*32 + lg*8);
    #pragma unroll
    for (int j=0;j<2;j++){
      int nt = wid*2 + j;
      bf16x8 b = *(const bf16x8*)(wWout + (size_t)(nt*16+lr)*DFF + ks*32 + lg*8);
      #pragma unroll
      for (int mt=0;mt<2;mt++)
        accO[mt][j] = __builtin_amdgcn_mfma_f32_16x16x32_bf16(a[mt], b, accO[mt][j], 0,0,0);
    }
  }
  #pragma unroll
  for (int j=0;j<2;j++){
    int col = (wid*2+j)*16 + lr;
    float bv = Woutb[col];
    #pragma unroll
    for (int mt=0;mt<2;mt++){
      #pragma unroll
      for (int e=0;e<4;e++){
        int row = mt*16 + lg*4 + e;
        float t = accO[mt][j][e] + bv + hmid[(size_t)(m0+row)*H + col];
        sT[row*132 + col] = t;
      }
    }
  }
  __syncthreads();

  // ---- LN2 + mask_V ----
  int row = tid>>3, part = tid&7;
  float s=0.f, q=0.f;
  #pragma unroll
  for (int jj=0;jj<16;jj++){
    float v = sT[row*132 + part*16 + jj];
    s += v; q += v*v;
  }
  s += __shfl_xor(s,1); q += __shfl_xor(q,1);
  s += __shfl_xor(s,2); q += __shfl_xor(q,2);
  s += __shfl_xor(s,4); q += __shfl_xor(q,4);
  float mu  = s*(1.0f/128.0f);
  float var = q*(1.0f/128.0f) - mu*mu;
  float rs  = rsqrtf(var + 1e-5f);
  float mv  = maskV[m0+row];
  #pragma unroll
  for (int jj=0;jj<16;jj++){
    int c = part*16 + jj;
    out[(size_t)(m0+row)*H + c] = mv * ((sT[row*132+c]-mu)*rs*ln2w[c] + ln2b[c]);
  }
}

extern "C" void kernel_launch(void* const* d_in, const int* in_sizes, int n_in,
                              void* d_out, int out_size, void* d_ws, size_t ws_size,
                              hipStream_t stream)
{
  const float* hV    = (const float*)d_in[0];
  const float* hE    = (const float*)d_in[1];
  const float* maskV = (const float*)d_in[2];
  const float* maskA = (const float*)d_in[3];
  const float* W1w   = (const float*)d_in[4];
  const float* W1b   = (const float*)d_in[5];
  const float* W2w   = (const float*)d_in[6];
  const float* W2b   = (const float*)d_in[7];
  const float* W3w   = (const float*)d_in[8];
  const float* W3b   = (const float*)d_in[9];
  const float* ln1w  = (const float*)d_in[10];
  const float* ln1b  = (const float*)d_in[11];
  const float* Winw  = (const float*)d_in[12];
  const float* Winb  = (const float*)d_in[13];
  const float* Woutw = (const float*)d_in[14];
  const float* Woutb = (const float*)d_in[15];
  const float* ln2w  = (const float*)d_in[16];
  const float* ln2b  = (const float*)d_in[17];

  unsigned short* wAll  = (unsigned short*)d_ws;
  unsigned short* wW1   = wAll;            // [128][512] bf16
  unsigned short* wW2   = wAll + 65536;    // [128][128]
  unsigned short* wW3   = wAll + 81920;    // [128][128]
  unsigned short* wWin  = wAll + 98304;    // [512][128]
  unsigned short* wWout = wAll + 163840;   // [128][512]
  float* bias1 = (float*)((char*)d_ws + 458752);   // [8192][128] f32 (4 MB)
  float* hmid  = (float*)d_out;                    // [8192][128] f32 — reuse d_out as scratch
  float* outp  = (float*)d_out;

  k_convert<<<224, 256, 0, stream>>>(W1w, W2w, W3w, Winw, Woutw, wAll);
  k_bias1  <<<128, 256, 0, stream>>>(hV, wW1, W1b, bias1);
  k_message<<<NNODES, 256, 0, stream>>>(hV, hE, maskA, wW1, wW2, wW3,
                                        W2b, W3b, ln1w, ln1b, bias1, hmid);
  k_ffn    <<<NNODES/32, 256, 0, stream>>>(hmid, wWin, wWout, Winb, Woutb,
                                           ln2w, ln2b, maskV, outp);
}

// Round 4
// 284.884 us; speedup vs baseline: 1.5938x; 1.5938x over previous
//
#include <hip/hip_runtime.h>
#include <hip/hip_bf16.h>

#define H    128
#define HIN  384
#define FIN  512      // H + HIN
#define KNB  48
#define DFF  512
#define NNODES 8192
#define NNB_F (KNB*HIN)   // floats of h_E per node

typedef float f32x4 __attribute__((ext_vector_type(4)));
typedef short bf16x8 __attribute__((ext_vector_type(8)));

__device__ __forceinline__ short bfs(float x){
  __hip_bfloat16 h = __float2bfloat16(x);   // RNE
  return *(short*)&h;
}

__device__ __forceinline__ bf16x8 pack8(float4 a, float4 b){
  bf16x8 o;
  o[0]=bfs(a.x); o[1]=bfs(a.y); o[2]=bfs(a.z); o[3]=bfs(a.w);
  o[4]=bfs(b.x); o[5]=bfs(b.y); o[6]=bfs(b.z); o[7]=bfs(b.w);
  return o;
}

__device__ __forceinline__ float gelu_f(float x){
  return 0.5f * x * (1.0f + erff(x * 0.70710678118654752f));
}

__device__ __forceinline__ f32x4 zero4(){ f32x4 z; z[0]=0.f;z[1]=0.f;z[2]=0.f;z[3]=0.f; return z; }

// ---------------- kernel 0: convert weights fp32 -> bf16 into ws ----------------
__global__ __launch_bounds__(256) void k_convert(
    const float* __restrict__ W1, const float* __restrict__ W2,
    const float* __restrict__ W3, const float* __restrict__ Win,
    const float* __restrict__ Wout, unsigned short* __restrict__ dst)
{
  int i0 = (blockIdx.x*256 + threadIdx.x)*4;
  #pragma unroll
  for (int t=0;t<4;t++){
    int idx = i0 + t;
    float v;
    if      (idx <  65536) v = W1[idx];
    else if (idx <  81920) v = W2[idx-65536];
    else if (idx <  98304) v = W3[idx-81920];
    else if (idx < 163840) v = Win[idx-98304];
    else                   v = Wout[idx-163840];
    dst[idx] = (unsigned short)bfs(v);
  }
}

// ---------------- kernel 1: bias1[node][o] = h_V @ W1[:, :128]^T + W1_b ----------------
__global__ __launch_bounds__(256) void k_bias1(
    const float* __restrict__ hV, const unsigned short* __restrict__ wW1,
    const float* __restrict__ W1b, float* __restrict__ bias1)
{
  int tid = threadIdx.x;
  int wid = tid>>6, lane = tid&63;
  int lr = lane&15, lg = lane>>4;
  int m0 = (blockIdx.x*4 + wid)*16;

  f32x4 acc[8];
  #pragma unroll
  for (int i=0;i<8;i++) acc[i] = zero4();

  #pragma unroll
  for (int ks=0; ks<4; ks++){
    const float* p = hV + (size_t)(m0+lr)*H + ks*32 + lg*8;
    bf16x8 a = pack8(*(const float4*)p, *(const float4*)(p+4));
    #pragma unroll
    for (int nt=0; nt<8; nt++){
      bf16x8 b = *(const bf16x8*)(wW1 + (size_t)(nt*16+lr)*FIN + ks*32 + lg*8);
      acc[nt] = __builtin_amdgcn_mfma_f32_16x16x32_bf16(a, b, acc[nt], 0,0,0);
    }
  }
  #pragma unroll
  for (int nt=0; nt<8; nt++){
    int col = nt*16 + lr;
    float bv = W1b[col];
    #pragma unroll
    for (int e=0;e<4;e++){
      int row = lg*4 + e;
      bias1[(size_t)(m0+row)*H + col] = acc[nt][e] + bv;
    }
  }
}

// ---------------- kernel 2: per-node message chain + LN1 ----------------
// grid = 8192 blocks (one node each), 256 threads (4 waves).
// h_E staged to LDS bf16 in 3 chunks of 128 cols, double-buffered:
// all global loads issued in the prologue (T14 issue-early), chunk c+1 is
// converted+written while GEMM1 computes chunk c. LDS 40.4KB -> 4 blocks/CU.
__global__ __launch_bounds__(256) void k_message(
    const float* __restrict__ hV, const float* __restrict__ hE,
    const float* __restrict__ maskA,
    const unsigned short* __restrict__ wW1, const unsigned short* __restrict__ wW2,
    const unsigned short* __restrict__ wW3,
    const float* __restrict__ W2b, const float* __restrict__ W3b,
    const float* __restrict__ ln1w, const float* __restrict__ ln1b,
    const float* __restrict__ bias1, float* __restrict__ hmid)
{
  __shared__ __align__(16) unsigned short sA[2][48*136]; // h_E chunk bf16, dbuf
  __shared__ __align__(16) unsigned short sG[48*136];    // G1 then G2 (reused)
  __shared__ float sMask[48];
  __shared__ float sBias[128];
  __shared__ float sDh[128];

  int node = blockIdx.x;
  int tid  = threadIdx.x;
  const float* hEn = hE + (size_t)node * NNB_F;

  int wid = tid>>6, lane = tid&63;
  int lr = lane&15, lg = lane>>4;

  // ---- prologue: issue ALL h_E loads; write chunk0 ----
  int sr = tid>>4, scg = tid&15;                 // stage row base / col-group
  const float* gp = hEn + (size_t)sr*HIN + scg*8;

  float4 c0[3][2], c1[3][2], c2[3][2];
  #pragma unroll
  for (int i=0;i<3;i++){
    const float* p = gp + i*16*HIN;
    c0[i][0] = *(const float4*)(p);       c0[i][1] = *(const float4*)(p+4);
  }
  #pragma unroll
  for (int i=0;i<3;i++){
    const float* p = gp + i*16*HIN + 128;
    c1[i][0] = *(const float4*)(p);       c1[i][1] = *(const float4*)(p+4);
  }
  #pragma unroll
  for (int i=0;i<3;i++){
    const float* p = gp + i*16*HIN + 256;
    c2[i][0] = *(const float4*)(p);       c2[i][1] = *(const float4*)(p+4);
  }
  if (tid < 48)  sMask[tid] = maskA[(size_t)node*KNB + tid];
  if (tid < 128) sBias[tid] = bias1[(size_t)node*H + tid];
  #pragma unroll
  for (int i=0;i<3;i++)
    *(bf16x8*)(&sA[0][(sr+16*i)*136 + scg*8]) = pack8(c0[i][0], c0[i][1]);
  __syncthreads();

  // ---- GEMM1: [48 x 384] @ W1e^T -> [48 x 128], chunked over K ----
  f32x4 acc1[3][2];
  #pragma unroll
  for (int mt=0;mt<3;mt++){ acc1[mt][0]=zero4(); acc1[mt][1]=zero4(); }

  auto gemm1_chunk = [&](const unsigned short* buf, int c){
    #pragma unroll
    for (int ks=0; ks<4; ks++){
      bf16x8 a[3];
      #pragma unroll
      for (int mt=0;mt<3;mt++)
        a[mt] = *(const bf16x8*)(buf + (mt*16+lr)*136 + ks*32 + lg*8);
      #pragma unroll
      for (int j=0;j<2;j++){
        int nt = wid*2 + j;
        bf16x8 b = *(const bf16x8*)(wW1 + (size_t)(nt*16+lr)*FIN + (H + c*128 + ks*32 + lg*8));
        #pragma unroll
        for (int mt=0;mt<3;mt++)
          acc1[mt][j] = __builtin_amdgcn_mfma_f32_16x16x32_bf16(a[mt], b, acc1[mt][j], 0,0,0);
      }
    }
  };

  gemm1_chunk(sA[0], 0);
  #pragma unroll
  for (int i=0;i<3;i++)
    *(bf16x8*)(&sA[1][(sr+16*i)*136 + scg*8]) = pack8(c1[i][0], c1[i][1]);
  __syncthreads();

  gemm1_chunk(sA[1], 1);
  #pragma unroll
  for (int i=0;i<3;i++)
    *(bf16x8*)(&sA[0][(sr+16*i)*136 + scg*8]) = pack8(c2[i][0], c2[i][1]);
  __syncthreads();

  gemm1_chunk(sA[0], 2);
  __syncthreads();

  // epilogue 1: + bias1, gelu, write G1
  #pragma unroll
  for (int j=0;j<2;j++){
    int col = (wid*2+j)*16 + lr;
    float bv = sBias[col];
    #pragma unroll
    for (int mt=0;mt<3;mt++){
      #pragma unroll
      for (int e=0;e<4;e++){
        float g = gelu_f(acc1[mt][j][e] + bv);
        int row = mt*16 + lg*4 + e;
        sG[row*136 + col] = (unsigned short)bfs(g);
      }
    }
  }
  __syncthreads();

  // ---- GEMM2: [48 x 128] @ W2^T ----
  f32x4 acc2[3][2];
  #pragma unroll
  for (int mt=0;mt<3;mt++){ acc2[mt][0]=zero4(); acc2[mt][1]=zero4(); }
  #pragma unroll
  for (int ks=0; ks<4; ks++){
    bf16x8 a[3];
    #pragma unroll
    for (int mt=0;mt<3;mt++)
      a[mt] = *(const bf16x8*)(sG + (mt*16+lr)*136 + ks*32 + lg*8);
    #pragma unroll
    for (int j=0;j<2;j++){
      int nt = wid*2 + j;
      bf16x8 b = *(const bf16x8*)(wW2 + (size_t)(nt*16+lr)*H + ks*32 + lg*8);
      #pragma unroll
      for (int mt=0;mt<3;mt++)
        acc2[mt][j] = __builtin_amdgcn_mfma_f32_16x16x32_bf16(a[mt], b, acc2[mt][j], 0,0,0);
    }
  }
  __syncthreads();   // all reads of G1 done before overwrite

  // epilogue 2: + b2, gelu, write G2 (same buffer)
  #pragma unroll
  for (int j=0;j<2;j++){
    int col = (wid*2+j)*16 + lr;
    float bv = W2b[col];
    #pragma unroll
    for (int mt=0;mt<3;mt++){
      #pragma unroll
      for (int e=0;e<4;e++){
        float g = gelu_f(acc2[mt][j][e] + bv);
        int row = mt*16 + lg*4 + e;
        sG[row*136 + col] = (unsigned short)bfs(g);
      }
    }
  }
  __syncthreads();

  // ---- GEMM3: [48 x 128] @ W3^T ----
  f32x4 acc3[3][2];
  #pragma unroll
  for (int mt=0;mt<3;mt++){ acc3[mt][0]=zero4(); acc3[mt][1]=zero4(); }
  #pragma unroll
  for (int ks=0; ks<4; ks++){
    bf16x8 a[3];
    #pragma unroll
    for (int mt=0;mt<3;mt++)
      a[mt] = *(const bf16x8*)(sG + (mt*16+lr)*136 + ks*32 + lg*8);
    #pragma unroll
    for (int j=0;j<2;j++){
      int nt = wid*2 + j;
      bf16x8 b = *(const bf16x8*)(wW3 + (size_t)(nt*16+lr)*H + ks*32 + lg*8);
      #pragma unroll
      for (int mt=0;mt<3;mt++)
        acc3[mt][j] = __builtin_amdgcn_mfma_f32_16x16x32_bf16(a[mt], b, acc3[mt][j], 0,0,0);
    }
  }
  // epilogue 3: + b3, * mask_attend, column-sum over the 48 rows
  #pragma unroll
  for (int j=0;j<2;j++){
    int col = (wid*2+j)*16 + lr;
    float bv = W3b[col];
    float p = 0.f;
    #pragma unroll
    for (int mt=0;mt<3;mt++){
      #pragma unroll
      for (int e=0;e<4;e++){
        int row = mt*16 + lg*4 + e;
        p += (acc3[mt][j][e] + bv) * sMask[row];
      }
    }
    p += __shfl_xor(p, 16);
    p += __shfl_xor(p, 32);
    if (lane < 16) sDh[(wid*2+j)*16 + lane] = p;
  }
  __syncthreads();

  // ---- LN1 (wave 0): h = LN(h_V + dh/30) -> hmid ----
  if (wid == 0){
    int c0i = lane, c1i = lane + 64;
    float t0 = hV[(size_t)node*H + c0i] + sDh[c0i]*(1.0f/30.0f);
    float t1 = hV[(size_t)node*H + c1i] + sDh[c1i]*(1.0f/30.0f);
    float s = t0 + t1, q = t0*t0 + t1*t1;
    #pragma unroll
    for (int off=1; off<64; off<<=1){ s += __shfl_xor(s, off); q += __shfl_xor(q, off); }
    float mu  = s * (1.0f/128.0f);
    float var = q * (1.0f/128.0f) - mu*mu;
    float rs  = rsqrtf(var + 1e-5f);
    hmid[(size_t)node*H + c0i] = (t0-mu)*rs*ln1w[c0i] + ln1b[c0i];
    hmid[(size_t)node*H + c1i] = (t1-mu)*rs*ln1w[c1i] + ln1b[c1i];
  }
}

// ---------------- kernel 3: FFN + LN2 + mask_V -> out (in place over hmid) ----------------
// grid = 256 blocks (32 nodes each), 256 threads
__global__ __launch_bounds__(256) void k_ffn(
    const float* __restrict__ hmid, const unsigned short* __restrict__ wWin,
    const unsigned short* __restrict__ wWout,
    const float* __restrict__ Winb, const float* __restrict__ Woutb,
    const float* __restrict__ ln2w, const float* __restrict__ ln2b,
    const float* __restrict__ maskV, float* __restrict__ out)
{
  __shared__ __align__(16) unsigned short sH[32*136];
  __shared__ __align__(16) unsigned short sU[32*520];
  __shared__ float sT[32*132];

  int tid = threadIdx.x;
  int m0 = blockIdx.x * 32;

  #pragma unroll
  for (int i=0;i<2;i++){
    int c = i*256 + tid;         // 512 chunks of 8
    int row = c>>4, cir = c&15;
    const float* p = hmid + (size_t)(m0+row)*H + cir*8;
    *(bf16x8*)(sH + row*136 + cir*8) = pack8(*(const float4*)p, *(const float4*)(p+4));
  }
  __syncthreads();

  int wid = tid>>6, lane = tid&63;
  int lr = lane&15, lg = lane>>4;

  // ---- GEMM in: [32 x 128] @ Win^T -> [32 x 512], gelu ----
  f32x4 acc[2][8];
  #pragma unroll
  for (int mt=0;mt<2;mt++)
    #pragma unroll
    for (int j=0;j<8;j++) acc[mt][j] = zero4();

  #pragma unroll
  for (int ks=0; ks<4; ks++){
    bf16x8 a[2];
    #pragma unroll
    for (int mt=0;mt<2;mt++)
      a[mt] = *(const bf16x8*)(sH + (mt*16+lr)*136 + ks*32 + lg*8);
    #pragma unroll
    for (int j=0;j<8;j++){
      int nt = wid*8 + j;
      bf16x8 b = *(const bf16x8*)(wWin + (size_t)(nt*16+lr)*H + ks*32 + lg*8);
      #pragma unroll
      for (int mt=0;mt<2;mt++)
        acc[mt][j] = __builtin_amdgcn_mfma_f32_16x16x32_bf16(a[mt], b, acc[mt][j], 0,0,0);
    }
  }
  #pragma unroll
  for (int j=0;j<8;j++){
    int col = (wid*8+j)*16 + lr;
    float bv = Winb[col];
    #pragma unroll
    for (int mt=0;mt<2;mt++){
      #pragma unroll
      for (int e=0;e<4;e++){
        float g = gelu_f(acc[mt][j][e] + bv);
        int row = mt*16 + lg*4 + e;
        sU[row*520 + col] = (unsigned short)bfs(g);
      }
    }
  }
  __syncthreads();

  // ---- GEMM out: [32 x 512] @ Wout^T -> [32 x 128], +bias +residual ----
  f32x4 accO[2][2];
  #pragma unroll
  for (int mt=0;mt<2;mt++){ accO[mt][0]=zero4(); accO[mt][1]=zero4(); }

  for (int ks=0; ks<16; ks++){
    bf16x8 a[2];
    #pragma unroll
    for (int mt=0;mt<2;mt++)
      a[mt] = *(const bf16x8*)(sU + (mt*16+lr)*520 + ks*32 + lg*8);
    #pragma unroll
    for (int j=0;j<2;j++){
      int nt = wid*2 + j;
      bf16x8 b = *(const bf16x8*)(wWout + (size_t)(nt*16+lr)*DFF + ks*32 + lg*8);
      #pragma unroll
      for (int mt=0;mt<2;mt++)
        accO[mt][j] = __builtin_amdgcn_mfma_f32_16x16x32_bf16(a[mt], b, accO[mt][j], 0,0,0);
    }
  }
  #pragma unroll
  for (int j=0;j<2;j++){
    int col = (wid*2+j)*16 + lr;
    float bv = Woutb[col];
    #pragma unroll
    for (int mt=0;mt<2;mt++){
      #pragma unroll
      for (int e=0;e<4;e++){
        int row = mt*16 + lg*4 + e;
        float t = accO[mt][j][e] + bv + hmid[(size_t)(m0+row)*H + col];
        sT[row*132 + col] = t;
      }
    }
  }
  __syncthreads();

  // ---- LN2 + mask_V ----
  int row = tid>>3, part = tid&7;
  float s=0.f, q=0.f;
  #pragma unroll
  for (int jj=0;jj<16;jj++){
    float v = sT[row*132 + part*16 + jj];
    s += v; q += v*v;
  }
  s += __shfl_xor(s,1); q += __shfl_xor(q,1);
  s += __shfl_xor(s,2); q += __shfl_xor(q,2);
  s += __shfl_xor(s,4); q += __shfl_xor(q,4);
  float mu  = s*(1.0f/128.0f);
  float var = q*(1.0f/128.0f) - mu*mu;
  float rs  = rsqrtf(var + 1e-5f);
  float mv  = maskV[m0+row];
  #pragma unroll
  for (int jj=0;jj<16;jj++){
    int c = part*16 + jj;
    out[(size_t)(m0+row)*H + c] = mv * ((sT[row*132+c]-mu)*rs*ln2w[c] + ln2b[c]);
  }
}

extern "C" void kernel_launch(void* const* d_in, const int* in_sizes, int n_in,
                              void* d_out, int out_size, void* d_ws, size_t ws_size,
                              hipStream_t stream)
{
  const float* hV    = (const float*)d_in[0];
  const float* hE    = (const float*)d_in[1];
  const float* maskV = (const float*)d_in[2];
  const float* maskA = (const float*)d_in[3];
  const float* W1w   = (const float*)d_in[4];
  const float* W1b   = (const float*)d_in[5];
  const float* W2w   = (const float*)d_in[6];
  const float* W2b   = (const float*)d_in[7];
  const float* W3w   = (const float*)d_in[8];
  const float* W3b   = (const float*)d_in[9];
  const float* ln1w  = (const float*)d_in[10];
  const float* ln1b  = (const float*)d_in[11];
  const float* Winw  = (const float*)d_in[12];
  const float* Winb  = (const float*)d_in[13];
  const float* Woutw = (const float*)d_in[14];
  const float* Woutb = (const float*)d_in[15];
  const float* ln2w  = (const float*)d_in[16];
  const float* ln2b  = (const float*)d_in[17];

  unsigned short* wAll  = (unsigned short*)d_ws;
  unsigned short* wW1   = wAll;            // [128][512] bf16
  unsigned short* wW2   = wAll + 65536;    // [128][128]
  unsigned short* wW3   = wAll + 81920;    // [128][128]
  unsigned short* wWin  = wAll + 98304;    // [512][128]
  unsigned short* wWout = wAll + 163840;   // [128][512]
  float* bias1 = (float*)((char*)d_ws + 458752);   // [8192][128] f32 (4 MB)
  float* hmid  = (float*)d_out;                    // [8192][128] f32 — reuse d_out as scratch
  float* outp  = (float*)d_out;

  k_convert<<<224, 256, 0, stream>>>(W1w, W2w, W3w, Winw, Woutw, wAll);
  k_bias1  <<<128, 256, 0, stream>>>(hV, wW1, W1b, bias1);
  k_message<<<NNODES, 256, 0, stream>>>(hV, hE, maskA, wW1, wW2, wW3,
                                        W2b, W3b, ln1w, ln1b, bias1, hmid);
  k_ffn    <<<NNODES/32, 256, 0, stream>>>(hmid, wWin, wWout, Winb, Woutb,
                                           ln2w, ln2b, maskV, outp);
}

// Round 5
// 249.598 us; speedup vs baseline: 1.8191x; 1.1414x over previous
//
#include <hip/hip_runtime.h>
#include <hip/hip_bf16.h>

#define H    128
#define HIN  384
#define FIN  512      // H + HIN
#define KNB  48
#define DFF  512
#define NNODES 8192
#define NNB_F (KNB*HIN)   // floats of h_E per node

typedef float f32x4 __attribute__((ext_vector_type(4)));
typedef short bf16x8 __attribute__((ext_vector_type(8)));

__device__ __forceinline__ short bfs(float x){
  __hip_bfloat16 h = __float2bfloat16(x);   // RNE
  return *(short*)&h;
}

__device__ __forceinline__ bf16x8 pack8(float4 a, float4 b){
  bf16x8 o;
  o[0]=bfs(a.x); o[1]=bfs(a.y); o[2]=bfs(a.z); o[3]=bfs(a.w);
  o[4]=bfs(b.x); o[5]=bfs(b.y); o[6]=bfs(b.z); o[7]=bfs(b.w);
  return o;
}

// fast gelu: tanh form, one v_exp_f32 + v_rcp_f32 (~8 VALU ops).
// max |err| vs exact erf-gelu ~1e-3, inside bf16 tolerance.
__device__ __forceinline__ float gelu_f(float x){
  float x2 = x*x;
  float z  = x * fmaf(0.0713548162726f, x2, 1.59576912161f); // 2*0.7978845608*(x+0.044715x^3)
  z = fminf(fmaxf(z, -30.f), 30.f);
  float e = __expf(z);
  return x * e * __builtin_amdgcn_rcpf(1.f + e);   // x * sigmoid(z)
}

__device__ __forceinline__ f32x4 zero4(){ f32x4 z; z[0]=0.f;z[1]=0.f;z[2]=0.f;z[3]=0.f; return z; }

// ---------------- kernel 0: convert weights fp32 -> bf16 into ws ----------------
__global__ __launch_bounds__(256) void k_convert(
    const float* __restrict__ W1, const float* __restrict__ W2,
    const float* __restrict__ W3, const float* __restrict__ Win,
    const float* __restrict__ Wout, unsigned short* __restrict__ dst)
{
  int i0 = (blockIdx.x*256 + threadIdx.x)*4;
  #pragma unroll
  for (int t=0;t<4;t++){
    int idx = i0 + t;
    float v;
    if      (idx <  65536) v = W1[idx];
    else if (idx <  81920) v = W2[idx-65536];
    else if (idx <  98304) v = W3[idx-81920];
    else if (idx < 163840) v = Win[idx-98304];
    else                   v = Wout[idx-163840];
    dst[idx] = (unsigned short)bfs(v);
  }
}

// ---------------- kernel 1: bias1[node][o] = h_V @ W1[:, :128]^T + W1_b ----------------
__global__ __launch_bounds__(256) void k_bias1(
    const float* __restrict__ hV, const unsigned short* __restrict__ wW1,
    const float* __restrict__ W1b, float* __restrict__ bias1)
{
  int tid = threadIdx.x;
  int wid = tid>>6, lane = tid&63;
  int lr = lane&15, lg = lane>>4;
  int m0 = (blockIdx.x*4 + wid)*16;

  f32x4 acc[8];
  #pragma unroll
  for (int i=0;i<8;i++) acc[i] = zero4();

  #pragma unroll
  for (int ks=0; ks<4; ks++){
    const float* p = hV + (size_t)(m0+lr)*H + ks*32 + lg*8;
    bf16x8 a = pack8(*(const float4*)p, *(const float4*)(p+4));
    #pragma unroll
    for (int nt=0; nt<8; nt++){
      bf16x8 b = *(const bf16x8*)(wW1 + (size_t)(nt*16+lr)*FIN + ks*32 + lg*8);
      acc[nt] = __builtin_amdgcn_mfma_f32_16x16x32_bf16(a, b, acc[nt], 0,0,0);
    }
  }
  #pragma unroll
  for (int nt=0; nt<8; nt++){
    int col = nt*16 + lr;
    float bv = W1b[col];
    #pragma unroll
    for (int e=0;e<4;e++){
      int row = lg*4 + e;
      bias1[(size_t)(m0+row)*H + col] = acc[nt][e] + bv;
    }
  }
}

// ---------------- kernel 2: per-node message chain + LN1 ----------------
// grid = 8192 blocks (one node each), 256 threads (4 waves).
// Two 48x136 LDS buffers only (27.3KB total -> 5 blocks/CU):
// chunks of h_E rotate b0,b1,b0 with 1-chunk register prefetch; G1->b1, G2->b0.
__global__ __launch_bounds__(256,5) void k_message(
    const float* __restrict__ hV, const float* __restrict__ hE,
    const float* __restrict__ maskA,
    const unsigned short* __restrict__ wW1, const unsigned short* __restrict__ wW2,
    const unsigned short* __restrict__ wW3,
    const float* __restrict__ W2b, const float* __restrict__ W3b,
    const float* __restrict__ ln1w, const float* __restrict__ ln1b,
    const float* __restrict__ bias1, float* __restrict__ hmid)
{
  __shared__ __align__(16) unsigned short sB0[48*136];
  __shared__ __align__(16) unsigned short sB1[48*136];
  __shared__ float sMask[48];
  __shared__ float sBias[128];
  __shared__ float sDh[128];

  int node = blockIdx.x;
  int tid  = threadIdx.x;
  const float* hEn = hE + (size_t)node * NNB_F;

  int wid = tid>>6, lane = tid&63;
  int lr = lane&15, lg = lane>>4;
  int sr = tid>>4, scg = tid&15;                 // stage row / col-group
  const float* gp = hEn + sr*HIN + scg*8;

  float4 pf[3][2];
  #pragma unroll
  for (int i=0;i<3;i++){
    const float* p = gp + i*16*HIN;
    pf[i][0] = *(const float4*)(p); pf[i][1] = *(const float4*)(p+4);
  }
  if (tid < 48)  sMask[tid] = maskA[(size_t)node*KNB + tid];
  if (tid < 128) sBias[tid] = bias1[(size_t)node*H + tid];
  #pragma unroll
  for (int i=0;i<3;i++)
    *(bf16x8*)(&sB0[(sr+16*i)*136 + scg*8]) = pack8(pf[i][0], pf[i][1]);
  __syncthreads();                                           // B0

  f32x4 acc1[3][2];
  #pragma unroll
  for (int mt=0;mt<3;mt++){ acc1[mt][0]=zero4(); acc1[mt][1]=zero4(); }

  auto gemm1_chunk = [&](const unsigned short* buf, int c){
    #pragma unroll
    for (int ks=0; ks<4; ks++){
      bf16x8 a[3];
      #pragma unroll
      for (int mt=0;mt<3;mt++)
        a[mt] = *(const bf16x8*)(buf + (mt*16+lr)*136 + ks*32 + lg*8);
      #pragma unroll
      for (int j=0;j<2;j++){
        int nt = wid*2 + j;
        bf16x8 b = *(const bf16x8*)(wW1 + (size_t)(nt*16+lr)*FIN + (H + c*128 + ks*32 + lg*8));
        #pragma unroll
        for (int mt=0;mt<3;mt++)
          acc1[mt][j] = __builtin_amdgcn_mfma_f32_16x16x32_bf16(a[mt], b, acc1[mt][j], 0,0,0);
      }
    }
  };

  // chunk1 prefetch || gemm chunk0
  #pragma unroll
  for (int i=0;i<3;i++){
    const float* p = gp + i*16*HIN + 128;
    pf[i][0] = *(const float4*)(p); pf[i][1] = *(const float4*)(p+4);
  }
  gemm1_chunk(sB0, 0);
  #pragma unroll
  for (int i=0;i<3;i++)
    *(bf16x8*)(&sB1[(sr+16*i)*136 + scg*8]) = pack8(pf[i][0], pf[i][1]);
  __syncthreads();                                           // B1

  // chunk2 prefetch || gemm chunk1
  #pragma unroll
  for (int i=0;i<3;i++){
    const float* p = gp + i*16*HIN + 256;
    pf[i][0] = *(const float4*)(p); pf[i][1] = *(const float4*)(p+4);
  }
  gemm1_chunk(sB1, 1);
  #pragma unroll
  for (int i=0;i<3;i++)
    *(bf16x8*)(&sB0[(sr+16*i)*136 + scg*8]) = pack8(pf[i][0], pf[i][1]);
  __syncthreads();                                           // B2

  gemm1_chunk(sB0, 2);

  // epilogue 1: + bias1, gelu, write G1 -> sB1 (chunk1 dead since B2)
  #pragma unroll
  for (int j=0;j<2;j++){
    int col = (wid*2+j)*16 + lr;
    float bv = sBias[col];
    #pragma unroll
    for (int mt=0;mt<3;mt++){
      #pragma unroll
      for (int e=0;e<4;e++){
        float g = gelu_f(acc1[mt][j][e] + bv);
        int row = mt*16 + lg*4 + e;
        sB1[row*136 + col] = (unsigned short)bfs(g);
      }
    }
  }
  __syncthreads();                                           // B3

  // ---- GEMM2: [48 x 128](G1 in sB1) @ W2^T ----
  f32x4 acc2[3][2];
  #pragma unroll
  for (int mt=0;mt<3;mt++){ acc2[mt][0]=zero4(); acc2[mt][1]=zero4(); }
  #pragma unroll
  for (int ks=0; ks<4; ks++){
    bf16x8 a[3];
    #pragma unroll
    for (int mt=0;mt<3;mt++)
      a[mt] = *(const bf16x8*)(sB1 + (mt*16+lr)*136 + ks*32 + lg*8);
    #pragma unroll
    for (int j=0;j<2;j++){
      int nt = wid*2 + j;
      bf16x8 b = *(const bf16x8*)(wW2 + (size_t)(nt*16+lr)*H + ks*32 + lg*8);
      #pragma unroll
      for (int mt=0;mt<3;mt++)
        acc2[mt][j] = __builtin_amdgcn_mfma_f32_16x16x32_bf16(a[mt], b, acc2[mt][j], 0,0,0);
    }
  }
  // epilogue 2: + b2, gelu, write G2 -> sB0 (chunk2 dead since B3)
  #pragma unroll
  for (int j=0;j<2;j++){
    int col = (wid*2+j)*16 + lr;
    float bv = W2b[col];
    #pragma unroll
    for (int mt=0;mt<3;mt++){
      #pragma unroll
      for (int e=0;e<4;e++){
        float g = gelu_f(acc2[mt][j][e] + bv);
        int row = mt*16 + lg*4 + e;
        sB0[row*136 + col] = (unsigned short)bfs(g);
      }
    }
  }
  __syncthreads();                                           // B4

  // ---- GEMM3: [48 x 128](G2 in sB0) @ W3^T ----
  f32x4 acc3[3][2];
  #pragma unroll
  for (int mt=0;mt<3;mt++){ acc3[mt][0]=zero4(); acc3[mt][1]=zero4(); }
  #pragma unroll
  for (int ks=0; ks<4; ks++){
    bf16x8 a[3];
    #pragma unroll
    for (int mt=0;mt<3;mt++)
      a[mt] = *(const bf16x8*)(sB0 + (mt*16+lr)*136 + ks*32 + lg*8);
    #pragma unroll
    for (int j=0;j<2;j++){
      int nt = wid*2 + j;
      bf16x8 b = *(const bf16x8*)(wW3 + (size_t)(nt*16+lr)*H + ks*32 + lg*8);
      #pragma unroll
      for (int mt=0;mt<3;mt++)
        acc3[mt][j] = __builtin_amdgcn_mfma_f32_16x16x32_bf16(a[mt], b, acc3[mt][j], 0,0,0);
    }
  }
  // epilogue 3: + b3, * mask_attend, column-sum over 48 rows
  #pragma unroll
  for (int j=0;j<2;j++){
    int col = (wid*2+j)*16 + lr;
    float bv = W3b[col];
    float p = 0.f;
    #pragma unroll
    for (int mt=0;mt<3;mt++){
      #pragma unroll
      for (int e=0;e<4;e++){
        int row = mt*16 + lg*4 + e;
        p += (acc3[mt][j][e] + bv) * sMask[row];
      }
    }
    p += __shfl_xor(p, 16);
    p += __shfl_xor(p, 32);
    if (lane < 16) sDh[(wid*2+j)*16 + lane] = p;
  }
  __syncthreads();                                           // B5

  // ---- LN1 (wave 0): h = LN(h_V + dh/30) -> hmid ----
  if (wid == 0){
    int c0i = lane, c1i = lane + 64;
    float t0 = hV[(size_t)node*H + c0i] + sDh[c0i]*(1.0f/30.0f);
    float t1 = hV[(size_t)node*H + c1i] + sDh[c1i]*(1.0f/30.0f);
    float s = t0 + t1, q = t0*t0 + t1*t1;
    #pragma unroll
    for (int off=1; off<64; off<<=1){ s += __shfl_xor(s, off); q += __shfl_xor(q, off); }
    float mu  = s * (1.0f/128.0f);
    float var = q * (1.0f/128.0f) - mu*mu;
    float rs  = rsqrtf(var + 1e-5f);
    hmid[(size_t)node*H + c0i] = (t0-mu)*rs*ln1w[c0i] + ln1b[c0i];
    hmid[(size_t)node*H + c1i] = (t1-mu)*rs*ln1w[c1i] + ln1b[c1i];
  }
}

// ---------------- kernel 3: FFN + LN2 + mask_V -> out (in place over hmid) ----------------
// grid = 256 blocks (32 nodes each), 256 threads
__global__ __launch_bounds__(256) void k_ffn(
    const float* __restrict__ hmid, const unsigned short* __restrict__ wWin,
    const unsigned short* __restrict__ wWout,
    const float* __restrict__ Winb, const float* __restrict__ Woutb,
    const float* __restrict__ ln2w, const float* __restrict__ ln2b,
    const float* __restrict__ maskV, float* __restrict__ out)
{
  __shared__ __align__(16) unsigned short sH[32*136];
  __shared__ __align__(16) unsigned short sU[32*520];
  __shared__ float sT[32*132];

  int tid = threadIdx.x;
  int m0 = blockIdx.x * 32;

  #pragma unroll
  for (int i=0;i<2;i++){
    int c = i*256 + tid;         // 512 chunks of 8
    int row = c>>4, cir = c&15;
    const float* p = hmid + (size_t)(m0+row)*H + cir*8;
    *(bf16x8*)(sH + row*136 + cir*8) = pack8(*(const float4*)p, *(const float4*)(p+4));
  }
  __syncthreads();

  int wid = tid>>6, lane = tid&63;
  int lr = lane&15, lg = lane>>4;

  // ---- GEMM in: [32 x 128] @ Win^T -> [32 x 512], gelu ----
  f32x4 acc[2][8];
  #pragma unroll
  for (int mt=0;mt<2;mt++)
    #pragma unroll
    for (int j=0;j<8;j++) acc[mt][j] = zero4();

  #pragma unroll
  for (int ks=0; ks<4; ks++){
    bf16x8 a[2];
    #pragma unroll
    for (int mt=0;mt<2;mt++)
      a[mt] = *(const bf16x8*)(sH + (mt*16+lr)*136 + ks*32 + lg*8);
    #pragma unroll
    for (int j=0;j<8;j++){
      int nt = wid*8 + j;
      bf16x8 b = *(const bf16x8*)(wWin + (size_t)(nt*16+lr)*H + ks*32 + lg*8);
      #pragma unroll
      for (int mt=0;mt<2;mt++)
        acc[mt][j] = __builtin_amdgcn_mfma_f32_16x16x32_bf16(a[mt], b, acc[mt][j], 0,0,0);
    }
  }
  #pragma unroll
  for (int j=0;j<8;j++){
    int col = (wid*8+j)*16 + lr;
    float bv = Winb[col];
    #pragma unroll
    for (int mt=0;mt<2;mt++){
      #pragma unroll
      for (int e=0;e<4;e++){
        float g = gelu_f(acc[mt][j][e] + bv);
        int row = mt*16 + lg*4 + e;
        sU[row*520 + col] = (unsigned short)bfs(g);
      }
    }
  }
  __syncthreads();

  // ---- GEMM out: [32 x 512] @ Wout^T -> [32 x 128], +bias +residual ----
  f32x4 accO[2][2];
  #pragma unroll
  for (int mt=0;mt<2;mt++){ accO[mt][0]=zero4(); accO[mt][1]=zero4(); }

  for (int ks=0; ks<16; ks++){
    bf16x8 a[2];
    #pragma unroll
    for (int mt=0;mt<2;mt++)
      a[mt] = *(const bf16x8*)(sU + (mt*16+lr)*520 + ks*32 + lg*8);
    #pragma unroll
    for (int j=0;j<2;j++){
      int nt = wid*2 + j;
      bf16x8 b = *(const bf16x8*)(wWout + (size_t)(nt*16+lr)*DFF + ks*32 + lg*8);
      #pragma unroll
      for (int mt=0;mt<2;mt++)
        accO[mt][j] = __builtin_amdgcn_mfma_f32_16x16x32_bf16(a[mt], b, accO[mt][j], 0,0,0);
    }
  }
  #pragma unroll
  for (int j=0;j<2;j++){
    int col = (wid*2+j)*16 + lr;
    float bv = Woutb[col];
    #pragma unroll
    for (int mt=0;mt<2;mt++){
      #pragma unroll
      for (int e=0;e<4;e++){
        int row = mt*16 + lg*4 + e;
        float t = accO[mt][j][e] + bv + hmid[(size_t)(m0+row)*H + col];
        sT[row*132 + col] = t;
      }
    }
  }
  __syncthreads();

  // ---- LN2 + mask_V ----
  int row = tid>>3, part = tid&7;
  float s=0.f, q=0.f;
  #pragma unroll
  for (int jj=0;jj<16;jj++){
    float v = sT[row*132 + part*16 + jj];
    s += v; q += v*v;
  }
  s += __shfl_xor(s,1); q += __shfl_xor(q,1);
  s += __shfl_xor(s,2); q += __shfl_xor(q,2);
  s += __shfl_xor(s,4); q += __shfl_xor(q,4);
  float mu  = s*(1.0f/128.0f);
  float var = q*(1.0f/128.0f) - mu*mu;
  float rs  = rsqrtf(var + 1e-5f);
  float mv  = maskV[m0+row];
  #pragma unroll
  for (int jj=0;jj<16;jj++){
    int c = part*16 + jj;
    out[(size_t)(m0+row)*H + c] = mv * ((sT[row*132+c]-mu)*rs*ln2w[c] + ln2b[c]);
  }
}

extern "C" void kernel_launch(void* const* d_in, const int* in_sizes, int n_in,
                              void* d_out, int out_size, void* d_ws, size_t ws_size,
                              hipStream_t stream)
{
  const float* hV    = (const float*)d_in[0];
  const float* hE    = (const float*)d_in[1];
  const float* maskV = (const float*)d_in[2];
  const float* maskA = (const float*)d_in[3];
  const float* W1w   = (const float*)d_in[4];
  const float* W1b   = (const float*)d_in[5];
  const float* W2w   = (const float*)d_in[6];
  const float* W2b   = (const float*)d_in[7];
  const float* W3w   = (const float*)d_in[8];
  const float* W3b   = (const float*)d_in[9];
  const float* ln1w  = (const float*)d_in[10];
  const float* ln1b  = (const float*)d_in[11];
  const float* Winw  = (const float*)d_in[12];
  const float* Winb  = (const float*)d_in[13];
  const float* Woutw = (const float*)d_in[14];
  const float* Woutb = (const float*)d_in[15];
  const float* ln2w  = (const float*)d_in[16];
  const float* ln2b  = (const float*)d_in[17];

  unsigned short* wAll  = (unsigned short*)d_ws;
  unsigned short* wW1   = wAll;            // [128][512] bf16
  unsigned short* wW2   = wAll + 65536;    // [128][128]
  unsigned short* wW3   = wAll + 81920;    // [128][128]
  unsigned short* wWin  = wAll + 98304;    // [512][128]
  unsigned short* wWout = wAll + 163840;   // [128][512]
  float* bias1 = (float*)((char*)d_ws + 458752);   // [8192][128] f32 (4 MB)
  float* hmid  = (float*)d_out;                    // [8192][128] f32 — reuse d_out as scratch
  float* outp  = (float*)d_out;

  k_convert<<<224, 256, 0, stream>>>(W1w, W2w, W3w, Winw, Woutw, wAll);
  k_bias1  <<<128, 256, 0, stream>>>(hV, wW1, W1b, bias1);
  k_message<<<NNODES, 256, 0, stream>>>(hV, hE, maskA, wW1, wW2, wW3,
                                        W2b, W3b, ln1w, ln1b, bias1, hmid);
  k_ffn    <<<NNODES/32, 256, 0, stream>>>(hmid, wWin, wWout, Winb, Woutb,
                                           ln2w, ln2b, maskV, outp);
}